// Round 14
// baseline (509.395 us; speedup 1.0000x reference)
//
#include <hip/hip_runtime.h>
#include <hip/hip_fp16.h>
#include <hip/hip_cooperative_groups.h>

#define NU 120000
#define NI 80000
#define NN 200000
#define DD 64
#define NE 1280000
#define BB 4096
#define NS 8192    // 2*B sampled nodes
#define NB2 196    // ceil(NN/1024) buckets, bucket = dst>>10
#define BCAP 8192  // slack capacity per bucket segment
#define CH2 1280   // coarse chunk: NE = 1000 * 1280 exactly
#define NCH 1000
#define GRID 512   // cooperative grid: needs only 2 blocks/CU co-resident
#define GSZ (GRID * 256)

namespace cg = cooperative_groups;

union SharedU {
  struct {
    int2 sv[CH2];
    unsigned char map8[CH2];
    int hist[256], lbase[256], gbase[256], s[256];
  } co;  // 15.6 KB
  struct {
    int cnt[1024], pre[1024], cur[1024];
    int s[256], bs[256];
  } fi;  // 14 KB
  struct {
    float sb[4][192];
  } at;  // 3 KB
};

// ===== Phase A body: conv | prep | build_s | zero cursors (grid-stride) =====
__device__ __forceinline__ void d_phaseA(int gtid, int stride, const float4* __restrict__ U4,
                                         const float4* __restrict__ V4, uint2* __restrict__ H0,
                                         const float* __restrict__ Wq,
                                         const float* __restrict__ Wk,
                                         const float* __restrict__ Wv,
                                         const float* __restrict__ Wo, float* __restrict__ Mt,
                                         float* __restrict__ Pm, const int* __restrict__ u,
                                         const int* __restrict__ ii, int* __restrict__ snodes,
                                         int* __restrict__ bcur, int* __restrict__ n2cnt) {
  const int NCONV = NN * 16;
  const int TOT = NCONV + 16384 + NS + 256;
  for (int i = gtid; i < TOT; i += stride) {
    if (i < NCONV) {
      int node = i >> 4, q = i & 15;
      float4 r = (node < NU) ? U4[(size_t)node * 16 + q] : V4[(size_t)(node - NU) * 16 + q];
      uint2 o;
      o.x = __builtin_bit_cast(unsigned int, __floats2half2_rn(r.x, r.y));
      o.y = __builtin_bit_cast(unsigned int, __floats2half2_rn(r.z, r.w));
      H0[(size_t)node * 16 + q] = o;
    } else if (i < NCONV + 16384) {
      int tt = i - NCONV;
      if (tt < 8192) {
        int h = tt >> 12, bb = (tt >> 6) & 63, j = tt & 63;
        float sa = 0.f;
        for (int k = 0; k < 32; ++k) sa += Wk[j * 64 + h * 32 + k] * Wq[bb * 64 + h * 32 + k];
        Mt[h * 4096 + bb * 64 + j] = sa;
      } else {
        int t2 = tt - 8192;
        int h = t2 >> 12, d = (t2 >> 6) & 63, j = t2 & 63;
        float sa = 0.f;
        for (int v = 0; v < 32; ++v) sa += Wv[d * 64 + h * 32 + v] * Wo[(h * 32 + v) * 64 + j];
        Pm[h * 4096 + d * 64 + j] = sa;
      }
    } else if (i < NCONV + 16384 + NS) {
      int tt = i - NCONV - 16384;
      snodes[tt] = (tt < BB) ? u[tt] : NU + ii[tt - BB];
    } else {
      int z = i - NCONV - 16384 - NS;
      if (z < NB2) bcur[z] = 0;
      else if (z == NB2) *n2cnt = 0;
    }
  }
}

// ===== coarse: LDS counting-sort; processes chunks b0, b0+nblk, ... =====
__device__ __forceinline__ void d_coarse_chunks(int b0, int nblk, const int* __restrict__ src,
                                                const int* __restrict__ dst,
                                                const float* __restrict__ val,
                                                int* __restrict__ bcur, int2* __restrict__ c_sv,
                                                SharedU& sh) {
  int t = threadIdx.x;
  for (int ch = b0; ch < NCH; ch += nblk) {
    sh.co.hist[t] = 0;
    __syncthreads();
    int e0 = ch * CH2;
    int d_[CH2 / 256];
#pragma unroll
    for (int k = 0; k < CH2 / 256; ++k) {
      int e = e0 + k * 256 + t;
      d_[k] = dst[e];
      atomicAdd(&sh.co.hist[d_[k] >> 10], 1);
    }
    __syncthreads();
    int x = sh.co.hist[t];
    sh.co.s[t] = x;
    __syncthreads();
    for (int off = 1; off < 256; off <<= 1) {
      int v = (t >= off) ? sh.co.s[t - off] : 0;
      __syncthreads();
      sh.co.s[t] += v;
      __syncthreads();
    }
    int lb = sh.co.s[t] - x;
    sh.co.lbase[t] = lb;
    sh.co.gbase[t] = (x && t < NB2) ? (t * BCAP + atomicAdd(&bcur[t], x)) : 0;
    for (int k = lb; k < lb + x; ++k) sh.co.map8[k] = (unsigned char)t;
    sh.co.hist[t] = 0;
    __syncthreads();
#pragma unroll
    for (int k = 0; k < CH2 / 256; ++k) {
      int e = e0 + k * 256 + t;
      int bk = d_[k] >> 10;
      int lp = sh.co.lbase[bk] + atomicAdd(&sh.co.hist[bk], 1);
      sh.co.sv[lp] = make_int2(src[e] | ((d_[k] & 1023) << 18), __float_as_int(val[e]));
    }
    __syncthreads();
    for (int sidx = t; sidx < CH2; sidx += 256) {
      int bk = sh.co.map8[sidx];
      c_sv[(size_t)sh.co.gbase[bk] + sidx - sh.co.lbase[bk]] = sh.co.sv[sidx];
    }
    __syncthreads();  // protect shared reuse on next chunk
  }
}

// ===== fine: one bucket -> row_ptr + pairs =====
__device__ __forceinline__ void d_fine_bucket(int b, const int* __restrict__ bcur,
                                              const int2* __restrict__ c_sv,
                                              int2* __restrict__ pairs,
                                              int* __restrict__ row_ptr, SharedU& sh) {
  int t = threadIdx.x;
  int bc = (t < NB2) ? bcur[t] : 0;
  sh.fi.bs[t] = bc;
  __syncthreads();
  for (int off = 1; off < 256; off <<= 1) {
    int v = (t >= off) ? sh.fi.bs[t - off] : 0;
    __syncthreads();
    sh.fi.bs[t] += v;
    __syncthreads();
  }
  int segN = bcur[b];
  int out0 = sh.fi.bs[b] - segN;
  int seg0 = b * BCAP;
  for (int k = t; k < 1024; k += 256) sh.fi.cnt[k] = 0;
  __syncthreads();
  for (int e = t; e < segN; e += 256) atomicAdd(&sh.fi.cnt[(c_sv[seg0 + e].x >> 18) & 1023], 1);
  __syncthreads();
  int a0 = sh.fi.cnt[4 * t], a1 = sh.fi.cnt[4 * t + 1];
  int a2 = sh.fi.cnt[4 * t + 2], a3 = sh.fi.cnt[4 * t + 3];
  int tot = a0 + a1 + a2 + a3;
  sh.fi.s[t] = tot;
  __syncthreads();
  for (int off = 1; off < 256; off <<= 1) {
    int v = (t >= off) ? sh.fi.s[t - off] : 0;
    __syncthreads();
    sh.fi.s[t] += v;
    __syncthreads();
  }
  int base = sh.fi.s[t] - tot;
  sh.fi.pre[4 * t] = base;
  sh.fi.pre[4 * t + 1] = base + a0;
  sh.fi.pre[4 * t + 2] = base + a0 + a1;
  sh.fi.pre[4 * t + 3] = base + a0 + a1 + a2;
  int node0 = b << 10;
#pragma unroll
  for (int k = 0; k < 4; ++k) {
    int n = node0 + 4 * t + k;
    if (n < NN) row_ptr[n] = out0 + sh.fi.pre[4 * t + k];
  }
  if (b == 0 && t == 0) row_ptr[NN] = NE;
  for (int k = t; k < 1024; k += 256) sh.fi.cur[k] = 0;
  __syncthreads();
  for (int e = t; e < segN; e += 256) {
    int2 svv = c_sv[seg0 + e];
    int ld = (svv.x >> 18) & 1023;
    int off = atomicAdd(&sh.fi.cur[ld], 1);
    pairs[out0 + sh.fi.pre[ld] + off] = make_int2(svv.x & 0x3FFFF, svv.y);
  }
}

// ===== gather0 (fp32 U||V -> Es[0]), grid-stride =====
__device__ __forceinline__ void d_gather0_gs(int rel, int nblk, const float4* __restrict__ U4,
                                             const float4* __restrict__ V4,
                                             float4* __restrict__ Es0,
                                             const int* __restrict__ snodes) {
  for (int i = rel * 256 + (int)threadIdx.x; i < NS * 16; i += nblk * 256) {
    int p = i >> 4, q = i & 15;
    int node = snodes[p];
    Es0[p * 16 + q] = (node < NU) ? U4[(size_t)node * 16 + q] : V4[(size_t)(node - NU) * 16 + q];
  }
}

// ===== fp16 table gather -> Es[l], grid-stride =====
__device__ __forceinline__ void d_gather_h_gs(int rel, int nblk, const uint2* __restrict__ Htab,
                                              float4* __restrict__ Es_l,
                                              const int* __restrict__ snodes) {
  for (int i = rel * 256 + (int)threadIdx.x; i < NS * 16; i += nblk * 256) {
    int p = i >> 4, q = i & 15;
    int node = snodes[p];
    uint2 r = Htab[(size_t)node * 16 + q];
    float2 f0 = __half22float2(__builtin_bit_cast(__half2, r.x));
    float2 f1 = __half22float2(__builtin_bit_cast(__half2, r.y));
    Es_l[p * 16 + q] = make_float4(f0.x, f0.y, f1.x, f1.y);
  }
}

// ===== nbrlist entry (idx < NS) =====
__device__ __forceinline__ void d_nbr(int idx, const int* __restrict__ snodes,
                                      const int* __restrict__ row_ptr,
                                      const int2* __restrict__ pairs, int* __restrict__ n2list,
                                      int* __restrict__ n2cnt) {
  if (idx >= NS) return;
  int node = snodes[idx];
  int s0 = row_ptr[node], e0 = row_ptr[node + 1];
  int pos = atomicAdd(n2cnt, e0 - s0 + 1);
  n2list[pos++] = node;
  for (int j = s0; j < e0; ++j) n2list[pos++] = pairs[j].x;
}

// ===== propagation: 8-lane group per node, 16B chunks, fp16 in, fp32 acc =====
template <int ULIST, int BYPOS, int OUTF32>
__device__ __forceinline__ void d_prop8(const uint4* __restrict__ Hin4,
                                        uint4* __restrict__ Hout4, float4* __restrict__ Fout,
                                        const int* __restrict__ row_ptr,
                                        const int2* __restrict__ pairs,
                                        const int* __restrict__ list,
                                        const int* __restrict__ countp, int cconst, int relbid,
                                        int nblk) {
  int n = countp ? *countp : cconst;
  int lane = threadIdx.x & 63;
  int c = lane & 7;
  int gb = lane & 56;
  int gstride = (nblk * 256) >> 3;
  for (int gid = (relbid * 256 + (int)threadIdx.x) >> 3; gid < n; gid += gstride) {
    int node = ULIST ? list[gid] : gid;
    int start = row_ptr[node], end = row_ptr[node + 1];
    float4 a0 = make_float4(0.f, 0.f, 0.f, 0.f);
    float4 a1 = make_float4(0.f, 0.f, 0.f, 0.f);
    for (int t0 = start; t0 < end; t0 += 8) {
      int cap = end - t0;
      if (cap > 8) cap = 8;
      int2 mp = pairs[t0 + (c < cap ? c : 0)];
      uint4 r[8];
      float vv[8];
#pragma unroll
      for (int k = 0; k < 8; ++k) {
        int srclane = gb + k;
        int sidx = __shfl(mp.x, srclane);
        float v = __int_as_float(__shfl(mp.y, srclane));
        vv[k] = (k < cap) ? v : 0.f;
        r[k] = Hin4[(size_t)sidx * 8 + c];
      }
#pragma unroll
      for (int k = 0; k < 8; ++k) {
        float2 f0 = __half22float2(__builtin_bit_cast(__half2, r[k].x));
        float2 f1 = __half22float2(__builtin_bit_cast(__half2, r[k].y));
        float2 f2 = __half22float2(__builtin_bit_cast(__half2, r[k].z));
        float2 f3 = __half22float2(__builtin_bit_cast(__half2, r[k].w));
        a0.x += vv[k] * f0.x;
        a0.y += vv[k] * f0.y;
        a0.z += vv[k] * f1.x;
        a0.w += vv[k] * f1.y;
        a1.x += vv[k] * f2.x;
        a1.y += vv[k] * f2.y;
        a1.z += vv[k] * f3.x;
        a1.w += vv[k] * f3.y;
      }
    }
    size_t op = BYPOS ? (size_t)gid : (size_t)node;
    if (OUTF32) {
      Fout[op * 16 + 2 * c] = a0;
      Fout[op * 16 + 2 * c + 1] = a1;
    } else {
      uint4 o;
      o.x = __builtin_bit_cast(unsigned int, __floats2half2_rn(a0.x, a0.y));
      o.y = __builtin_bit_cast(unsigned int, __floats2half2_rn(a0.z, a0.w));
      o.z = __builtin_bit_cast(unsigned int, __floats2half2_rn(a1.x, a1.y));
      o.w = __builtin_bit_cast(unsigned int, __floats2half2_rn(a1.z, a1.w));
      Hout4[op * 8 + c] = o;
    }
  }
}

// ===== attention + dot, grid-stride over pair blocks =====
__device__ __forceinline__ void d_attn_gs(int b, int nblk, const float* __restrict__ Es,
                                          const float* __restrict__ Mt,
                                          const float* __restrict__ Pm, float* __restrict__ out,
                                          float* sbw) {
  int wv = threadIdx.x >> 6, lane = threadIdx.x & 63;
  (void)wv;
  const float inv_scale = 0.17677669529663687f;  // 1/sqrt(32)
  const float* M0 = Mt;
  const float* M1 = Mt + 4096;
  const float* P0 = Pm;
  const float* P1 = Pm + 4096;
  for (int wi = b; wi * 4 < BB; wi += nblk) {
    int w = wi * 4 + (threadIdx.x >> 6);
    float eo[2];
#pragma unroll
    for (int side = 0; side < 2; ++side) {
      int p = side ? (BB + w) : w;
      float e0 = Es[(size_t)0 * NS * DD + p * DD + lane];
      float e1 = Es[(size_t)1 * NS * DD + p * DD + lane];
      float e2 = Es[(size_t)2 * NS * DD + p * DD + lane];
      float e3 = Es[(size_t)3 * NS * DD + p * DD + lane];
      sbw[lane] = e0;

      float g0 = 0.f, g1 = 0.f;
#pragma unroll 8
      for (int bb = 0; bb < 64; ++bb) {
        float eb = sbw[bb];
        g0 = fmaf(M0[bb * 64 + lane], eb, g0);
        g1 = fmaf(M1[bb * 64 + lane], eb, g1);
      }

      float el[4] = {e0, e1, e2, e3};
      float sc[4][2];
#pragma unroll
      for (int l = 0; l < 4; ++l) {
        float p0 = el[l] * g0, p1 = el[l] * g1;
#pragma unroll
        for (int o = 32; o; o >>= 1) {
          p0 += __shfl_xor(p0, o);
          p1 += __shfl_xor(p1, o);
        }
        sc[l][0] = p0 * inv_scale;
        sc[l][1] = p1 * inv_scale;
      }

      float ebar[2];
#pragma unroll
      for (int h = 0; h < 2; ++h) {
        float m = fmaxf(fmaxf(sc[0][h], sc[1][h]), fmaxf(sc[2][h], sc[3][h]));
        float x0 = expf(sc[0][h] - m), x1 = expf(sc[1][h] - m);
        float x2 = expf(sc[2][h] - m), x3 = expf(sc[3][h] - m);
        float inv = 1.f / (x0 + x1 + x2 + x3);
        ebar[h] = (x0 * e0 + x1 * e1 + x2 * e2 + x3 * e3) * inv;
      }
      sbw[64 + lane] = ebar[0];
      sbw[128 + lane] = ebar[1];

      float o = 0.f;
#pragma unroll 8
      for (int d = 0; d < 64; ++d) {
        float b0 = sbw[64 + d];
        float b1 = sbw[128 + d];
        o = fmaf(P0[d * 64 + lane], b0, o);
        o = fmaf(P1[d * 64 + lane], b1, o);
      }
      eo[side] = o;
    }
    float pd = eo[0] * eo[1];
#pragma unroll
    for (int o = 32; o; o >>= 1) pd += __shfl_xor(pd, o);
    if (lane == 0) out[w] = pd;
  }
}

// ================= cooperative mega-kernel =================
__global__ void __launch_bounds__(256, 2)
k_mega(const int* __restrict__ src, const int* __restrict__ dst, const float* __restrict__ val,
       const float4* __restrict__ U4, const float4* __restrict__ V4,
       const float* __restrict__ Wq, const float* __restrict__ Wk,
       const float* __restrict__ Wv, const float* __restrict__ Wo, const int* __restrict__ u,
       const int* __restrict__ ii, uint2* __restrict__ H0, uint2* __restrict__ H1,
       uint2* __restrict__ H2, float4* __restrict__ Es4, float* __restrict__ Mt,
       float* __restrict__ Pm, int* __restrict__ row_ptr, int* __restrict__ bcur,
       int* __restrict__ snodes, int* __restrict__ n2cnt, int2* __restrict__ pairs,
       int2* __restrict__ c_sv, int* __restrict__ n2list, float* __restrict__ out) {
  __shared__ SharedU sh;
  cg::grid_group grid = cg::this_grid();
  int b = blockIdx.x, t = threadIdx.x;

  d_phaseA(b * 256 + t, GSZ, U4, V4, H0, Wq, Wk, Wv, Wo, Mt, Pm, u, ii, snodes, bcur, n2cnt);
  grid.sync();

  d_coarse_chunks(b, GRID, src, dst, val, bcur, c_sv, sh);
  grid.sync();

  if (b < NB2) d_fine_bucket(b, bcur, c_sv, pairs, row_ptr, sh);
  else d_gather0_gs(b - NB2, GRID - NB2, U4, V4, Es4, snodes);
  grid.sync();

  if (b < 32) d_nbr(b * 256 + t, snodes, row_ptr, pairs, n2list, n2cnt);
  else d_prop8<0, 0, 0>((const uint4*)H0, (uint4*)H1, nullptr, row_ptr, pairs, nullptr, nullptr,
                        NN, b - 32, GRID - 32);
  grid.sync();

  if (b < 128) d_gather_h_gs(b, 128, H1, Es4 + (size_t)1 * NS * 16, snodes);
  else d_prop8<1, 0, 0>((const uint4*)H1, (uint4*)H2, nullptr, row_ptr, pairs, n2list, n2cnt, 0,
                        b - 128, GRID - 128);
  grid.sync();

  if (b < 128) d_gather_h_gs(b, 128, H2, Es4 + (size_t)2 * NS * 16, snodes);
  else d_prop8<1, 1, 1>((const uint4*)H2, nullptr, Es4 + (size_t)3 * NS * 16, row_ptr, pairs,
                        snodes, nullptr, NS, b - 128, GRID - 128);
  grid.sync();

  d_attn_gs(b, GRID, (const float*)Es4, Mt, Pm, out, sh.at.sb[t >> 6]);
}

// ================= fallback kernels (run iff cooperative launch fails) =================
__global__ void fb_A(const float4* U4, const float4* V4, uint2* H0, const float* Wq,
                     const float* Wk, const float* Wv, const float* Wo, float* Mt, float* Pm,
                     const int* u, const int* ii, int* snodes, int* bcur, int* n2cnt) {
  d_phaseA(blockIdx.x * 256 + threadIdx.x, 1024 * 256, U4, V4, H0, Wq, Wk, Wv, Wo, Mt, Pm, u, ii,
           snodes, bcur, n2cnt);
}
__global__ void fb_B(const int* src, const int* dst, const float* val, int* bcur, int2* c_sv) {
  __shared__ SharedU sh;
  d_coarse_chunks(blockIdx.x, NCH, src, dst, val, bcur, c_sv, sh);
}
__global__ void fb_C(const int* bcur, const int2* c_sv, int2* pairs, int* row_ptr,
                     const float4* U4, const float4* V4, float4* Es0, const int* snodes) {
  __shared__ SharedU sh;
  if (blockIdx.x < NB2) d_fine_bucket(blockIdx.x, bcur, c_sv, pairs, row_ptr, sh);
  else d_gather0_gs(blockIdx.x - NB2, 512, U4, V4, Es0, snodes);
}
__global__ void fb_D(const uint4* H04, uint4* H14, const int* row_ptr, const int2* pairs,
                     const int* snodes, int* n2list, int* n2cnt) {
  if (blockIdx.x < 32) d_nbr(blockIdx.x * 256 + threadIdx.x, snodes, row_ptr, pairs, n2list, n2cnt);
  else d_prop8<0, 0, 0>(H04, H14, nullptr, row_ptr, pairs, nullptr, nullptr, NN, blockIdx.x - 32,
                        2048);
}
__global__ void fb_E(const uint4* H14, uint4* H24, const uint2* H1, float4* Es1,
                     const int* snodes, const int* row_ptr, const int2* pairs, const int* n2list,
                     const int* n2cnt) {
  if (blockIdx.x < 512) d_gather_h_gs(blockIdx.x, 512, H1, Es1, snodes);
  else d_prop8<1, 0, 0>(H14, H24, nullptr, row_ptr, pairs, n2list, n2cnt, 0, blockIdx.x - 512,
                        1024);
}
__global__ void fb_F(const uint4* H24, const uint2* H2, float4* Es2, float4* Es3,
                     const int* snodes, const int* row_ptr, const int2* pairs) {
  if (blockIdx.x < 512) d_gather_h_gs(blockIdx.x, 512, H2, Es2, snodes);
  else d_prop8<1, 1, 1>(H24, nullptr, Es3, row_ptr, pairs, snodes, nullptr, NS, blockIdx.x - 512,
                        512);
}
__global__ void fb_G(const float* Es, const float* Mt, const float* Pm, float* out) {
  __shared__ SharedU sh;
  d_attn_gs(blockIdx.x, 1024, Es, Mt, Pm, out, sh.at.sb[threadIdx.x >> 6]);
}

extern "C" void kernel_launch(void* const* d_in, const int* in_sizes, int n_in,
                              void* d_out, int out_size, void* d_ws, size_t ws_size,
                              hipStream_t stream) {
  const int* edge_src = (const int*)d_in[0];
  const int* edge_dst = (const int*)d_in[1];
  const float* edge_val = (const float*)d_in[2];
  const float4* U4 = (const float4*)d_in[3];
  const float4* V4 = (const float4*)d_in[4];
  const float* Wq = (const float*)d_in[5];
  const float* Wk = (const float*)d_in[6];
  const float* Wv = (const float*)d_in[7];
  const float* Wo = (const float*)d_in[8];
  const int* u = (const int*)d_in[9];
  const int* ii = (const int*)d_in[10];
  float* out = (float*)d_out;

  // workspace layout
  float* Ea = (float*)d_ws;                          // H0 | H1 (fp16 tables)
  float* Eb = Ea + (size_t)NN * DD;                  // H2 (aliases c_sv scratch)
  float* Es = Eb + (size_t)NN * DD;                  // 4*NS*64 fp32
  float* Mt = Es + (size_t)4 * NS * DD;
  float* Pm = Mt + 8192;
  int* row_ptr = (int*)(Pm + 8192);                  // NN+1 (+pad)
  int* bcur = row_ptr + NN + 4;                      // NB2
  int* snodes = bcur + NB2;                          // NS
  int* n2cnt = snodes + NS;                          // 1
  uintptr_t pa = (uintptr_t)(n2cnt + 1);
  pa = (pa + 15) & ~(uintptr_t)15;
  int2* pairs = (int2*)pa;                           // NE int2

  uint2* H0 = (uint2*)Ea;
  uint2* H1 = H0 + (size_t)NN * 16;
  uint2* H2 = (uint2*)Eb;
  int2* c_sv = (int2*)Eb;
  int* n2list = (int*)(Es + (size_t)3 * NS * DD);

  float4* Es4 = (float4*)Es;

  void* args[] = {(void*)&edge_src, (void*)&edge_dst, (void*)&edge_val, (void*)&U4, (void*)&V4,
                  (void*)&Wq,       (void*)&Wk,       (void*)&Wv,       (void*)&Wo, (void*)&u,
                  (void*)&ii,       (void*)&H0,       (void*)&H1,       (void*)&H2, (void*)&Es4,
                  (void*)&Mt,       (void*)&Pm,       (void*)&row_ptr,  (void*)&bcur,
                  (void*)&snodes,   (void*)&n2cnt,    (void*)&pairs,    (void*)&c_sv,
                  (void*)&n2list,   (void*)&out};
  hipError_t err =
      hipLaunchCooperativeKernel((const void*)k_mega, dim3(GRID), dim3(256), args, 0, stream);
  if (err != hipSuccess) {
    (void)hipGetLastError();  // clear sticky error; deterministic fallback path
    fb_A<<<1024, 256, 0, stream>>>(U4, V4, H0, Wq, Wk, Wv, Wo, Mt, Pm, u, ii, snodes, bcur,
                                   n2cnt);
    fb_B<<<NCH, 256, 0, stream>>>(edge_src, edge_dst, edge_val, bcur, c_sv);
    fb_C<<<NB2 + 512, 256, 0, stream>>>(bcur, c_sv, pairs, row_ptr, U4, V4, Es4, snodes);
    fb_D<<<32 + 2048, 256, 0, stream>>>((const uint4*)H0, (uint4*)H1, row_ptr, pairs, snodes,
                                        n2list, n2cnt);
    fb_E<<<512 + 1024, 256, 0, stream>>>((const uint4*)H1, (uint4*)H2, H1,
                                         Es4 + (size_t)1 * NS * 16, snodes, row_ptr, pairs,
                                         n2list, n2cnt);
    fb_F<<<512 + 512, 256, 0, stream>>>((const uint4*)H2, H2, Es4 + (size_t)2 * NS * 16,
                                        Es4 + (size_t)3 * NS * 16, snodes, row_ptr, pairs);
    fb_G<<<1024, 256, 0, stream>>>((const float*)Es4, Mt, Pm, out);
  }
}

// Round 15
// 130.169 us; speedup vs baseline: 3.9133x; 3.9133x over previous
//
#include <hip/hip_runtime.h>
#include <hip/hip_fp16.h>

#define NU 120000
#define NI 80000
#define NN 200000
#define DD 64
#define NE 1280000
#define BB 4096
#define NS 8192    // 2*B sampled nodes
#define NB2 196    // ceil(NN/1024) buckets, bucket = dst>>10
#define BCAP 8192  // slack capacity per bucket segment (mean 6530, +20 sigma)
#define CH2 4096   // coarse chunk
#define CB 313     // ceil(NE/CH2)

// fine4m mega-kernel block partition
#define FB 196
#define CONVB 3125     // conv blocks = NN*16/(256*4)
#define PREPB 64
#define BSB 32
// prop1 mega-kernel partition
#define P1B 2048
#define NLB 32         // NS/256

// ---------------- pre: zero cursors/counters ----------------
__global__ void k_pre(int* __restrict__ bcur, int* __restrict__ n2cnt) {
  int t = threadIdx.x;
  if (t < NB2) bcur[t] = 0;
  if (t == 0) *n2cnt = 0;
}

// ---------------- coarse: LDS counting-sort of 4096 edges into 196 buckets ----------------
__global__ void k_coarse2(const int* __restrict__ src, const int* __restrict__ dst,
                          const float* __restrict__ val, int* __restrict__ bcur,
                          int2* __restrict__ c_sv) {
  __shared__ int2 sv[CH2];             // 32KB sorted staging
  __shared__ unsigned char map8[CH2];  // slot -> bucket
  __shared__ int hist[256];
  __shared__ int lbase[256];
  __shared__ int gbase[256];
  __shared__ int s[256];
  int t = threadIdx.x;
  hist[t] = 0;
  __syncthreads();
  int e0 = blockIdx.x * CH2;
  int d_[CH2 / 256];
#pragma unroll
  for (int k = 0; k < CH2 / 256; ++k) {
    int e = e0 + k * 256 + t;
    d_[k] = (e < NE) ? dst[e] : -1;
    if (d_[k] >= 0) atomicAdd(&hist[d_[k] >> 10], 1);
  }
  __syncthreads();
  int x = hist[t];
  s[t] = x;
  __syncthreads();
  for (int off = 1; off < 256; off <<= 1) {
    int v = (t >= off) ? s[t - off] : 0;
    __syncthreads();
    s[t] += v;
    __syncthreads();
  }
  int lb = s[t] - x;
  lbase[t] = lb;
  gbase[t] = (x && t < NB2) ? (t * BCAP + atomicAdd(&bcur[t], x)) : 0;
  for (int k = lb; k < lb + x; ++k) map8[k] = (unsigned char)t;
  hist[t] = 0;  // reuse as in-block cursor
  __syncthreads();
#pragma unroll
  for (int k = 0; k < CH2 / 256; ++k) {
    int e = e0 + k * 256 + t;
    if (d_[k] >= 0) {
      int b = d_[k] >> 10;
      int lp = lbase[b] + atomicAdd(&hist[b], 1);
      sv[lp] = make_int2(src[e] | ((d_[k] & 1023) << 18), __float_as_int(val[e]));
    }
  }
  __syncthreads();
  int nval = NE - e0;
  if (nval > CH2) nval = CH2;
  for (int sidx = t; sidx < nval; sidx += 256) {
    int b = map8[sidx];
    c_sv[(size_t)gbase[b] + sidx - lbase[b]] = sv[sidx];  // coalesced runs
  }
}

// ---------------- device bodies for fine4m ----------------
__device__ __forceinline__ void d_conv(int rel, const float4* __restrict__ U4,
                                       const float4* __restrict__ V4, uint2* __restrict__ H0) {
  int t = threadIdx.x;
  float4 r[4];
#pragma unroll
  for (int k = 0; k < 4; ++k) {
    int idx = rel * 1024 + k * 256 + t;
    int node = idx >> 4, q = idx & 15;
    r[k] = (node < NU) ? U4[(size_t)node * 16 + q] : V4[(size_t)(node - NU) * 16 + q];
  }
#pragma unroll
  for (int k = 0; k < 4; ++k) {
    int idx = rel * 1024 + k * 256 + t;
    __half2 a = __floats2half2_rn(r[k].x, r[k].y);
    __half2 b = __floats2half2_rn(r[k].z, r[k].w);
    uint2 o;
    o.x = __builtin_bit_cast(unsigned int, a);
    o.y = __builtin_bit_cast(unsigned int, b);
    H0[idx] = o;
  }
}

__device__ __forceinline__ void d_prep(int rel, const float* __restrict__ Wq,
                                       const float* __restrict__ Wk, const float* __restrict__ Wv,
                                       const float* __restrict__ Wo, float* __restrict__ Mt,
                                       float* __restrict__ P) {
  int t = rel * 256 + threadIdx.x;
  if (t < 8192) {
    int h = t >> 12;
    int b = (t >> 6) & 63;
    int j = t & 63;
    float s = 0.f;
    for (int k = 0; k < 32; ++k) s += Wk[j * 64 + h * 32 + k] * Wq[b * 64 + h * 32 + k];
    Mt[h * 4096 + b * 64 + j] = s;
  } else if (t < 16384) {
    int t2 = t - 8192;
    int h = t2 >> 12;
    int d = (t2 >> 6) & 63;
    int j = t2 & 63;
    float s = 0.f;
    for (int v = 0; v < 32; ++v) s += Wv[d * 64 + h * 32 + v] * Wo[(h * 32 + v) * 64 + j];
    P[h * 4096 + d * 64 + j] = s;
  }
}

// ---------------- FINE4M mega-kernel: fine4b | conv | prep | build_s ----------------
__global__ void k_fine4m(const int* __restrict__ bcur, const int2* __restrict__ c_sv,
                         int2* __restrict__ pairs, int* __restrict__ row_ptr,
                         const float4* __restrict__ U4, const float4* __restrict__ V4,
                         uint2* __restrict__ H0, const float* __restrict__ Wq,
                         const float* __restrict__ Wk, const float* __restrict__ Wv,
                         const float* __restrict__ Wo, float* __restrict__ Mt,
                         float* __restrict__ P, const int* __restrict__ u,
                         const int* __restrict__ ii, int* __restrict__ snodes) {
  __shared__ int cnt[1024];
  __shared__ int pre[1024];
  __shared__ int cur[1024];
  __shared__ int s[256];
  __shared__ int bs[256];
  int b = blockIdx.x, t = threadIdx.x;
  if (b >= FB) {
    int r = b - FB;
    if (r < CONVB) {
      d_conv(r, U4, V4, H0);
    } else if (r < CONVB + PREPB) {
      d_prep(r - CONVB, Wq, Wk, Wv, Wo, Mt, P);
    } else {
      int tt = (r - CONVB - PREPB) * 256 + t;
      if (tt < NS) snodes[tt] = (tt < BB) ? u[tt] : NU + ii[tt - BB];
    }
    return;
  }
  // ---- fine4b body: one block per bucket ----
  int bc = (t < NB2) ? bcur[t] : 0;
  bs[t] = bc;
  __syncthreads();
  for (int off = 1; off < 256; off <<= 1) {
    int v = (t >= off) ? bs[t - off] : 0;
    __syncthreads();
    bs[t] += v;
    __syncthreads();
  }
  int segN = bcur[b];
  int out0 = bs[b] - segN;
  int seg0 = b * BCAP;
  for (int k = t; k < 1024; k += 256) cnt[k] = 0;
  __syncthreads();
  for (int e = t; e < segN; e += 256) atomicAdd(&cnt[(c_sv[seg0 + e].x >> 18) & 1023], 1);
  __syncthreads();
  int a0 = cnt[4 * t], a1 = cnt[4 * t + 1], a2 = cnt[4 * t + 2], a3 = cnt[4 * t + 3];
  int tot = a0 + a1 + a2 + a3;
  s[t] = tot;
  __syncthreads();
  for (int off = 1; off < 256; off <<= 1) {
    int v = (t >= off) ? s[t - off] : 0;
    __syncthreads();
    s[t] += v;
    __syncthreads();
  }
  int base = s[t] - tot;
  pre[4 * t] = base;
  pre[4 * t + 1] = base + a0;
  pre[4 * t + 2] = base + a0 + a1;
  pre[4 * t + 3] = base + a0 + a1 + a2;
  int node0 = b << 10;
#pragma unroll
  for (int k = 0; k < 4; ++k) {
    int n = node0 + 4 * t + k;
    if (n < NN) row_ptr[n] = out0 + pre[4 * t + k];
  }
  if (b == 0 && t == 0) row_ptr[NN] = NE;
  for (int k = t; k < 1024; k += 256) cur[k] = 0;
  __syncthreads();
  for (int e = t; e < segN; e += 256) {
    int2 svv = c_sv[seg0 + e];
    int ld = (svv.x >> 18) & 1023;
    int off = atomicAdd(&cur[ld], 1);
    pairs[out0 + pre[ld] + off] = make_int2(svv.x & 0x3FFFF, svv.y);
  }
}

// ---------------- propagation: 16-lane group per node, fp16 in, fp32 acc ----------------
template <int ULIST, int BYPOS, int OUTF32>
__device__ __forceinline__ void d_prop(const uint2* __restrict__ Hin, uint2* __restrict__ Hout,
                                       float4* __restrict__ Fout,
                                       const int* __restrict__ row_ptr,
                                       const int2* __restrict__ pairs,
                                       const int* __restrict__ list,
                                       const int* __restrict__ countp, int cconst, int relbid,
                                       int nblk) {
  int n = countp ? *countp : cconst;
  int lane = threadIdx.x & 63;
  int c = lane & 15;
  int sl = c & 7;
  int gstride = (nblk * 256) >> 4;
  for (int gid = (relbid * 256 + (int)threadIdx.x) >> 4; gid < n; gid += gstride) {
    int node = ULIST ? list[gid] : gid;
    int start = row_ptr[node], end = row_ptr[node + 1];
    float4 acc = make_float4(0.f, 0.f, 0.f, 0.f);
    for (int t0 = start; t0 < end; t0 += 8) {
      int cap = end - t0;
      if (cap > 8) cap = 8;
      int2 mp = pairs[t0 + (sl < cap ? sl : 0)];  // coalesced tile-index load
      uint2 r[8];
      float vv[8];
#pragma unroll
      for (int k = 0; k < 8; ++k) {
        int srclane = (lane & 48) + k;
        int sidx = __shfl(mp.x, srclane);
        float v = __int_as_float(__shfl(mp.y, srclane));
        vv[k] = (k < cap) ? v : 0.f;
        r[k] = Hin[(size_t)sidx * 16 + c];  // 8 independent 8B gathers in flight
      }
#pragma unroll
      for (int k = 0; k < 8; ++k) {
        float2 f0 = __half22float2(__builtin_bit_cast(__half2, r[k].x));
        float2 f1 = __half22float2(__builtin_bit_cast(__half2, r[k].y));
        acc.x += vv[k] * f0.x;
        acc.y += vv[k] * f0.y;
        acc.z += vv[k] * f1.x;
        acc.w += vv[k] * f1.y;
      }
    }
    size_t op = BYPOS ? (size_t)gid : (size_t)node;
    if (OUTF32) {
      Fout[op * 16 + c] = acc;
    } else {
      __half2 a = __floats2half2_rn(acc.x, acc.y);
      __half2 bq = __floats2half2_rn(acc.z, acc.w);
      uint2 o;
      o.x = __builtin_bit_cast(unsigned int, a);
      o.y = __builtin_bit_cast(unsigned int, bq);
      Hout[op * 16 + c] = o;
    }
  }
}

// ---------------- PROP1 mega-kernel: prop1-all | nbrlist ----------------
__global__ void k_prop1m(const uint2* __restrict__ H0, uint2* __restrict__ H1,
                         const int* __restrict__ snodes, const int* __restrict__ row_ptr,
                         const int2* __restrict__ pairs, int* __restrict__ n2list,
                         int* __restrict__ n2cnt) {
  int b = blockIdx.x;
  if (b < P1B) {
    d_prop<0, 0, 0>(H0, H1, nullptr, row_ptr, pairs, nullptr, nullptr, NN, b, P1B);
  } else {
    int idx = (b - P1B) * 256 + threadIdx.x;
    if (idx < NS) {
      int node = snodes[idx];
      int s0 = row_ptr[node], e0 = row_ptr[node + 1];
      int pos = atomicAdd(n2cnt, e0 - s0 + 1);
      n2list[pos++] = node;
      for (int j = s0; j < e0; ++j) n2list[pos++] = pairs[j].x;
    }
  }
}

// ---------------- STAGE2: prop2 over n2list (dupes benign) ----------------
__global__ void k_stage2(const uint2* __restrict__ H1, uint2* __restrict__ H2,
                         const int* __restrict__ row_ptr, const int2* __restrict__ pairs,
                         const int* __restrict__ n2list, const int* __restrict__ n2cnt) {
  d_prop<1, 0, 0>(H1, H2, nullptr, row_ptr, pairs, n2list, n2cnt, 0, blockIdx.x, 1536);
}

// ---------------- STAGE3: prop3 (samples -> Es3 fp32) ----------------
__global__ void k_stage3(const uint2* __restrict__ H2, float4* __restrict__ Es3,
                         const int* __restrict__ snodes, const int* __restrict__ row_ptr,
                         const int2* __restrict__ pairs) {
  d_prop<1, 1, 1>(H2, nullptr, Es3, row_ptr, pairs, snodes, nullptr, NS, blockIdx.x, 512);
}

// ---------------- fused attention + pair scoring: reads sources directly ----------------
__global__ void k_attn3(const float* __restrict__ Uf, const float* __restrict__ Vf,
                        const __half* __restrict__ H1h, const __half* __restrict__ H2h,
                        const float* __restrict__ Es3, const int* __restrict__ snodes,
                        const float* __restrict__ Mt, const float* __restrict__ P,
                        float* __restrict__ out) {
  __shared__ float sb[4][3 * 64];
  int wv = threadIdx.x >> 6, lane = threadIdx.x & 63;
  int w = blockIdx.x * 4 + wv;
  if (w >= BB) return;
  const float inv_scale = 0.17677669529663687f;  // 1/sqrt(32)
  const float* M0 = Mt;
  const float* M1 = Mt + 4096;
  const float* P0 = P;
  const float* P1 = P + 4096;
  float eo[2];
#pragma unroll
  for (int side = 0; side < 2; ++side) {
    int p = side ? (BB + w) : w;
    int node = snodes[p];
    float e0 = (node < NU) ? Uf[(size_t)node * DD + lane] : Vf[(size_t)(node - NU) * DD + lane];
    float e1 = __half2float(H1h[(size_t)node * DD + lane]);
    float e2 = __half2float(H2h[(size_t)node * DD + lane]);
    float e3 = Es3[(size_t)p * DD + lane];
    sb[wv][lane] = e0;

    float g0 = 0.f, g1 = 0.f;
#pragma unroll 8
    for (int b = 0; b < 64; ++b) {
      float eb = sb[wv][b];  // LDS same-address broadcast (wave-synchronous)
      g0 = fmaf(M0[b * 64 + lane], eb, g0);
      g1 = fmaf(M1[b * 64 + lane], eb, g1);
    }

    float el[4] = {e0, e1, e2, e3};
    float sc[4][2];
#pragma unroll
    for (int l = 0; l < 4; ++l) {
      float p0 = el[l] * g0, p1 = el[l] * g1;
#pragma unroll
      for (int o = 32; o; o >>= 1) {
        p0 += __shfl_xor(p0, o);
        p1 += __shfl_xor(p1, o);
      }
      sc[l][0] = p0 * inv_scale;
      sc[l][1] = p1 * inv_scale;
    }

    float ebar[2];
#pragma unroll
    for (int h = 0; h < 2; ++h) {
      float m = fmaxf(fmaxf(sc[0][h], sc[1][h]), fmaxf(sc[2][h], sc[3][h]));
      float x0 = expf(sc[0][h] - m), x1 = expf(sc[1][h] - m);
      float x2 = expf(sc[2][h] - m), x3 = expf(sc[3][h] - m);
      float inv = 1.f / (x0 + x1 + x2 + x3);
      ebar[h] = (x0 * e0 + x1 * e1 + x2 * e2 + x3 * e3) * inv;
    }
    sb[wv][64 + lane] = ebar[0];
    sb[wv][128 + lane] = ebar[1];

    float o = 0.f;
#pragma unroll 8
    for (int d = 0; d < 64; ++d) {
      float b0 = sb[wv][64 + d];
      float b1 = sb[wv][128 + d];
      o = fmaf(P0[d * 64 + lane], b0, o);
      o = fmaf(P1[d * 64 + lane], b1, o);
    }
    eo[side] = o;
  }
  float pd = eo[0] * eo[1];
#pragma unroll
  for (int o = 32; o; o >>= 1) pd += __shfl_xor(pd, o);
  if (lane == 0) out[w] = pd;
}

extern "C" void kernel_launch(void* const* d_in, const int* in_sizes, int n_in,
                              void* d_out, int out_size, void* d_ws, size_t ws_size,
                              hipStream_t stream) {
  const int* edge_src = (const int*)d_in[0];
  const int* edge_dst = (const int*)d_in[1];
  const float* edge_val = (const float*)d_in[2];
  const float* U_emb = (const float*)d_in[3];
  const float* V_emb = (const float*)d_in[4];
  const float* Wq = (const float*)d_in[5];
  const float* Wk = (const float*)d_in[6];
  const float* Wv = (const float*)d_in[7];
  const float* Wo = (const float*)d_in[8];
  const int* u = (const int*)d_in[9];
  const int* ii = (const int*)d_in[10];
  float* out = (float*)d_out;

  const float4* U4 = (const float4*)U_emb;
  const float4* V4 = (const float4*)V_emb;

  // workspace layout (16B-aligned base)
  float* Ea = (float*)d_ws;                          // H0 | H1 (fp16 tables, 25.6MB each)
  float* Eb = Ea + (size_t)NN * DD;                  // H2 (aliases c_sv scratch before)
  float* Es = Eb + (size_t)NN * DD;                  // 4*NS*64 fp32 (quarters 0-2 unused)
  float* Mt = Es + (size_t)4 * NS * DD;              // 2*4096
  float* Pm = Mt + 8192;                             // 2*4096
  int* row_ptr = (int*)(Pm + 8192);                  // NN+1 (+pad)
  int* bcur = row_ptr + NN + 4;                      // NB2
  int* snodes = bcur + NB2;                          // NS
  int* n2cnt = snodes + NS;                          // 1
  uintptr_t pa = (uintptr_t)(n2cnt + 1);
  pa = (pa + 15) & ~(uintptr_t)15;
  int2* pairs = (int2*)pa;                           // NE int2

  uint2* H0 = (uint2*)Ea;                 // NN*16 uint2
  uint2* H1 = H0 + (size_t)NN * 16;
  uint2* H2 = (uint2*)Eb;                 // written after c_sv dead
  int2* c_sv = (int2*)Eb;                 // NB2*BCAP int2 = 12.8MB — dead after k_fine4m
  int* n2list = (int*)Es;                 // Es quarter 0 (never otherwise written)
  float4* Es3 = (float4*)Es + (size_t)3 * NS * 16;

  k_pre<<<1, 256, 0, stream>>>(bcur, n2cnt);
  k_coarse2<<<CB, 256, 0, stream>>>(edge_src, edge_dst, edge_val, bcur, c_sv);
  k_fine4m<<<FB + CONVB + PREPB + BSB, 256, 0, stream>>>(bcur, c_sv, pairs, row_ptr, U4, V4, H0,
                                                         Wq, Wk, Wv, Wo, Mt, Pm, u, ii, snodes);
  k_prop1m<<<P1B + NLB, 256, 0, stream>>>(H0, H1, snodes, row_ptr, pairs, n2list, n2cnt);
  k_stage2<<<1536, 256, 0, stream>>>(H1, H2, row_ptr, pairs, n2list, n2cnt);
  k_stage3<<<512, 256, 0, stream>>>(H2, Es3, snodes, row_ptr, pairs);
  k_attn3<<<(BB + 3) / 4, 256, 0, stream>>>(U_emb, V_emb, (const __half*)H1, (const __half*)H2,
                                            (const float*)Es3, snodes, Mt, Pm, out);
}

// Round 16
// 127.831 us; speedup vs baseline: 3.9849x; 1.0183x over previous
//
#include <hip/hip_runtime.h>
#include <hip/hip_fp16.h>

#define NU 120000
#define NI 80000
#define NN 200000
#define DD 64
#define NE 1280000
#define BB 4096
#define NS 8192    // 2*B sampled nodes
#define NB2 196    // ceil(NN/1024) buckets, bucket = dst>>10
#define BCAP 8192  // slack capacity per bucket segment (mean 6530, +20 sigma)
#define CH2 4096   // coarse chunk
#define CB 313     // ceil(NE/CH2)

// fine4m mega-kernel block partition
#define FB 196
#define CONVB 3125     // conv blocks = NN*16/(256*4)
#define PREPB 64
#define BSB 32
// prop1 mega-kernel partition
#define P1B 2048
#define NLB 32         // NS/256

// ---------------- pre: zero cursors/counters ----------------
__global__ void k_pre(int* __restrict__ bcur, int* __restrict__ n2cnt) {
  int t = threadIdx.x;
  if (t < NB2) bcur[t] = 0;
  if (t == 0) *n2cnt = 0;
}

// ---------------- coarse: LDS counting-sort of 4096 edges into 196 buckets ----------------
__global__ void k_coarse2(const int* __restrict__ src, const int* __restrict__ dst,
                          const float* __restrict__ val, int* __restrict__ bcur,
                          int2* __restrict__ c_sv) {
  __shared__ int2 sv[CH2];             // 32KB sorted staging
  __shared__ unsigned char map8[CH2];  // slot -> bucket
  __shared__ int hist[256];
  __shared__ int lbase[256];
  __shared__ int gbase[256];
  __shared__ int s[256];
  int t = threadIdx.x;
  hist[t] = 0;
  __syncthreads();
  int e0 = blockIdx.x * CH2;
  int d_[CH2 / 256];
#pragma unroll
  for (int k = 0; k < CH2 / 256; ++k) {
    int e = e0 + k * 256 + t;
    d_[k] = (e < NE) ? dst[e] : -1;
    if (d_[k] >= 0) atomicAdd(&hist[d_[k] >> 10], 1);
  }
  __syncthreads();
  int x = hist[t];
  s[t] = x;
  __syncthreads();
  for (int off = 1; off < 256; off <<= 1) {
    int v = (t >= off) ? s[t - off] : 0;
    __syncthreads();
    s[t] += v;
    __syncthreads();
  }
  int lb = s[t] - x;
  lbase[t] = lb;
  gbase[t] = (x && t < NB2) ? (t * BCAP + atomicAdd(&bcur[t], x)) : 0;
  for (int k = lb; k < lb + x; ++k) map8[k] = (unsigned char)t;
  hist[t] = 0;  // reuse as in-block cursor
  __syncthreads();
#pragma unroll
  for (int k = 0; k < CH2 / 256; ++k) {
    int e = e0 + k * 256 + t;
    if (d_[k] >= 0) {
      int b = d_[k] >> 10;
      int lp = lbase[b] + atomicAdd(&hist[b], 1);
      sv[lp] = make_int2(src[e] | ((d_[k] & 1023) << 18), __float_as_int(val[e]));
    }
  }
  __syncthreads();
  int nval = NE - e0;
  if (nval > CH2) nval = CH2;
  for (int sidx = t; sidx < nval; sidx += 256) {
    int b = map8[sidx];
    c_sv[(size_t)gbase[b] + sidx - lbase[b]] = sv[sidx];  // coalesced runs
  }
}

// ---------------- device bodies for fine4m ----------------
__device__ __forceinline__ void d_conv(int rel, const float4* __restrict__ U4,
                                       const float4* __restrict__ V4, uint2* __restrict__ H0) {
  int t = threadIdx.x;
  float4 r[4];
#pragma unroll
  for (int k = 0; k < 4; ++k) {
    int idx = rel * 1024 + k * 256 + t;
    int node = idx >> 4, q = idx & 15;
    r[k] = (node < NU) ? U4[(size_t)node * 16 + q] : V4[(size_t)(node - NU) * 16 + q];
  }
#pragma unroll
  for (int k = 0; k < 4; ++k) {
    int idx = rel * 1024 + k * 256 + t;
    __half2 a = __floats2half2_rn(r[k].x, r[k].y);
    __half2 b = __floats2half2_rn(r[k].z, r[k].w);
    uint2 o;
    o.x = __builtin_bit_cast(unsigned int, a);
    o.y = __builtin_bit_cast(unsigned int, b);
    H0[idx] = o;
  }
}

__device__ __forceinline__ void d_prep(int rel, const float* __restrict__ Wq,
                                       const float* __restrict__ Wk, const float* __restrict__ Wv,
                                       const float* __restrict__ Wo, float* __restrict__ Mt,
                                       float* __restrict__ P) {
  int t = rel * 256 + threadIdx.x;
  if (t < 8192) {
    int h = t >> 12;
    int b = (t >> 6) & 63;
    int j = t & 63;
    float s = 0.f;
    for (int k = 0; k < 32; ++k) s += Wk[j * 64 + h * 32 + k] * Wq[b * 64 + h * 32 + k];
    Mt[h * 4096 + b * 64 + j] = s;
  } else if (t < 16384) {
    int t2 = t - 8192;
    int h = t2 >> 12;
    int d = (t2 >> 6) & 63;
    int j = t2 & 63;
    float s = 0.f;
    for (int v = 0; v < 32; ++v) s += Wv[d * 64 + h * 32 + v] * Wo[(h * 32 + v) * 64 + j];
    P[h * 4096 + d * 64 + j] = s;
  }
}

// ---------------- FINE4M mega-kernel: fine4b | conv | prep | build_s ----------------
__global__ void k_fine4m(const int* __restrict__ bcur, const int2* __restrict__ c_sv,
                         int2* __restrict__ pairs, int* __restrict__ row_ptr,
                         const float4* __restrict__ U4, const float4* __restrict__ V4,
                         uint2* __restrict__ H0, const float* __restrict__ Wq,
                         const float* __restrict__ Wk, const float* __restrict__ Wv,
                         const float* __restrict__ Wo, float* __restrict__ Mt,
                         float* __restrict__ P, const int* __restrict__ u,
                         const int* __restrict__ ii, int* __restrict__ snodes) {
  __shared__ int cnt[1024];
  __shared__ int pre[1024];
  __shared__ int cur[1024];
  __shared__ int s[256];
  __shared__ int bs[256];
  int b = blockIdx.x, t = threadIdx.x;
  if (b >= FB) {
    int r = b - FB;
    if (r < CONVB) {
      d_conv(r, U4, V4, H0);
    } else if (r < CONVB + PREPB) {
      d_prep(r - CONVB, Wq, Wk, Wv, Wo, Mt, P);
    } else {
      int tt = (r - CONVB - PREPB) * 256 + t;
      if (tt < NS) snodes[tt] = (tt < BB) ? u[tt] : NU + ii[tt - BB];
    }
    return;
  }
  // ---- fine4b body: one block per bucket ----
  int bc = (t < NB2) ? bcur[t] : 0;
  bs[t] = bc;
  __syncthreads();
  for (int off = 1; off < 256; off <<= 1) {
    int v = (t >= off) ? bs[t - off] : 0;
    __syncthreads();
    bs[t] += v;
    __syncthreads();
  }
  int segN = bcur[b];
  int out0 = bs[b] - segN;
  int seg0 = b * BCAP;
  for (int k = t; k < 1024; k += 256) cnt[k] = 0;
  __syncthreads();
  for (int e = t; e < segN; e += 256) atomicAdd(&cnt[(c_sv[seg0 + e].x >> 18) & 1023], 1);
  __syncthreads();
  int a0 = cnt[4 * t], a1 = cnt[4 * t + 1], a2 = cnt[4 * t + 2], a3 = cnt[4 * t + 3];
  int tot = a0 + a1 + a2 + a3;
  s[t] = tot;
  __syncthreads();
  for (int off = 1; off < 256; off <<= 1) {
    int v = (t >= off) ? s[t - off] : 0;
    __syncthreads();
    s[t] += v;
    __syncthreads();
  }
  int base = s[t] - tot;
  pre[4 * t] = base;
  pre[4 * t + 1] = base + a0;
  pre[4 * t + 2] = base + a0 + a1;
  pre[4 * t + 3] = base + a0 + a1 + a2;
  int node0 = b << 10;
#pragma unroll
  for (int k = 0; k < 4; ++k) {
    int n = node0 + 4 * t + k;
    if (n < NN) row_ptr[n] = out0 + pre[4 * t + k];
  }
  if (b == 0 && t == 0) row_ptr[NN] = NE;
  for (int k = t; k < 1024; k += 256) cur[k] = 0;
  __syncthreads();
  for (int e = t; e < segN; e += 256) {
    int2 svv = c_sv[seg0 + e];
    int ld = (svv.x >> 18) & 1023;
    int off = atomicAdd(&cur[ld], 1);
    pairs[out0 + pre[ld] + off] = make_int2(svv.x & 0x3FFFF, svv.y);
  }
}

// ---------------- propagation: 16-lane group per node, fp16 in, fp32 acc ----------------
template <int ULIST>
__device__ __forceinline__ void d_prop(const uint2* __restrict__ Hin, uint2* __restrict__ Hout,
                                       const int* __restrict__ row_ptr,
                                       const int2* __restrict__ pairs,
                                       const int* __restrict__ list,
                                       const int* __restrict__ countp, int cconst, int relbid,
                                       int nblk) {
  int n = countp ? *countp : cconst;
  int lane = threadIdx.x & 63;
  int c = lane & 15;
  int sl = c & 7;
  int gstride = (nblk * 256) >> 4;
  for (int gid = (relbid * 256 + (int)threadIdx.x) >> 4; gid < n; gid += gstride) {
    int node = ULIST ? list[gid] : gid;
    int start = row_ptr[node], end = row_ptr[node + 1];
    float4 acc = make_float4(0.f, 0.f, 0.f, 0.f);
    for (int t0 = start; t0 < end; t0 += 8) {
      int cap = end - t0;
      if (cap > 8) cap = 8;
      int2 mp = pairs[t0 + (sl < cap ? sl : 0)];  // coalesced tile-index load
      uint2 r[8];
      float vv[8];
#pragma unroll
      for (int k = 0; k < 8; ++k) {
        int srclane = (lane & 48) + k;
        int sidx = __shfl(mp.x, srclane);
        float v = __int_as_float(__shfl(mp.y, srclane));
        vv[k] = (k < cap) ? v : 0.f;
        r[k] = Hin[(size_t)sidx * 16 + c];  // 8 independent 8B gathers in flight
      }
#pragma unroll
      for (int k = 0; k < 8; ++k) {
        float2 f0 = __half22float2(__builtin_bit_cast(__half2, r[k].x));
        float2 f1 = __half22float2(__builtin_bit_cast(__half2, r[k].y));
        acc.x += vv[k] * f0.x;
        acc.y += vv[k] * f0.y;
        acc.z += vv[k] * f1.x;
        acc.w += vv[k] * f1.y;
      }
    }
    __half2 a = __floats2half2_rn(acc.x, acc.y);
    __half2 bq = __floats2half2_rn(acc.z, acc.w);
    uint2 o;
    o.x = __builtin_bit_cast(unsigned int, a);
    o.y = __builtin_bit_cast(unsigned int, bq);
    Hout[(size_t)node * 16 + c] = o;
  }
}

// ---------------- PROP1 mega-kernel: prop1-all | nbrlist ----------------
__global__ void k_prop1m(const uint2* __restrict__ H0, uint2* __restrict__ H1,
                         const int* __restrict__ snodes, const int* __restrict__ row_ptr,
                         const int2* __restrict__ pairs, int* __restrict__ n2list,
                         int* __restrict__ n2cnt) {
  int b = blockIdx.x;
  if (b < P1B) {
    d_prop<0>(H0, H1, row_ptr, pairs, nullptr, nullptr, NN, b, P1B);
  } else {
    int idx = (b - P1B) * 256 + threadIdx.x;
    if (idx < NS) {
      int node = snodes[idx];
      int s0 = row_ptr[node], e0 = row_ptr[node + 1];
      int pos = atomicAdd(n2cnt, e0 - s0 + 1);
      n2list[pos++] = node;
      for (int j = s0; j < e0; ++j) n2list[pos++] = pairs[j].x;
    }
  }
}

// ---------------- STAGE2: prop2 over n2list (dupes benign) ----------------
__global__ void k_stage2(const uint2* __restrict__ H1, uint2* __restrict__ H2,
                         const int* __restrict__ row_ptr, const int2* __restrict__ pairs,
                         const int* __restrict__ n2list, const int* __restrict__ n2cnt) {
  d_prop<1>(H1, H2, row_ptr, pairs, n2list, n2cnt, 0, blockIdx.x, 1536);
}

// ---------------- fused attention + inline E3-prop + pair scoring ----------------
__global__ void k_attn4(const float* __restrict__ Uf, const float* __restrict__ Vf,
                        const __half* __restrict__ H1h, const __half* __restrict__ H2h,
                        const int* __restrict__ snodes, const int* __restrict__ row_ptr,
                        const int2* __restrict__ pairs, const float* __restrict__ Mt,
                        const float* __restrict__ P, float* __restrict__ out) {
  __shared__ float sb[4][3 * 64];
  int wv = threadIdx.x >> 6, lane = threadIdx.x & 63;
  int w = blockIdx.x * 4 + wv;
  if (w >= BB) return;
  const float inv_scale = 0.17677669529663687f;  // 1/sqrt(32)
  const float* M0 = Mt;
  const float* M1 = Mt + 4096;
  const float* P0 = P;
  const float* P1 = P + 4096;
  float eo[2];
#pragma unroll
  for (int side = 0; side < 2; ++side) {
    int p = side ? (BB + w) : w;
    int node = snodes[p];
    float e0 = (node < NU) ? Uf[(size_t)node * DD + lane] : Vf[(size_t)(node - NU) * DD + lane];
    float e1 = __half2float(H1h[(size_t)node * DD + lane]);
    float e2 = __half2float(H2h[(size_t)node * DD + lane]);

    // e3 = (A @ H2)[node] computed inline (same tile-8 order as d_prop -> bit-identical)
    float e3 = 0.f;
    {
      int start = row_ptr[node], end = row_ptr[node + 1];
      int sl = lane & 7;
      for (int t0 = start; t0 < end; t0 += 8) {
        int cap = end - t0;
        if (cap > 8) cap = 8;
        int2 mp = pairs[t0 + (sl < cap ? sl : 0)];
        __half r[8];
        float vv[8];
#pragma unroll
        for (int k = 0; k < 8; ++k) {
          int sidx = __shfl(mp.x, k);
          float v = __int_as_float(__shfl(mp.y, k));
          vv[k] = (k < cap) ? v : 0.f;
          r[k] = H2h[(size_t)sidx * DD + lane];  // 8 independent row loads
        }
#pragma unroll
        for (int k = 0; k < 8; ++k) e3 += vv[k] * __half2float(r[k]);
      }
    }
    sb[wv][lane] = e0;

    float g0 = 0.f, g1 = 0.f;
#pragma unroll 8
    for (int b = 0; b < 64; ++b) {
      float eb = sb[wv][b];  // LDS same-address broadcast (wave-synchronous)
      g0 = fmaf(M0[b * 64 + lane], eb, g0);
      g1 = fmaf(M1[b * 64 + lane], eb, g1);
    }

    float el[4] = {e0, e1, e2, e3};
    float sc[4][2];
#pragma unroll
    for (int l = 0; l < 4; ++l) {
      float p0 = el[l] * g0, p1 = el[l] * g1;
#pragma unroll
      for (int o = 32; o; o >>= 1) {
        p0 += __shfl_xor(p0, o);
        p1 += __shfl_xor(p1, o);
      }
      sc[l][0] = p0 * inv_scale;
      sc[l][1] = p1 * inv_scale;
    }

    float ebar[2];
#pragma unroll
    for (int h = 0; h < 2; ++h) {
      float m = fmaxf(fmaxf(sc[0][h], sc[1][h]), fmaxf(sc[2][h], sc[3][h]));
      float x0 = expf(sc[0][h] - m), x1 = expf(sc[1][h] - m);
      float x2 = expf(sc[2][h] - m), x3 = expf(sc[3][h] - m);
      float inv = 1.f / (x0 + x1 + x2 + x3);
      ebar[h] = (x0 * e0 + x1 * e1 + x2 * e2 + x3 * e3) * inv;
    }
    sb[wv][64 + lane] = ebar[0];
    sb[wv][128 + lane] = ebar[1];

    float o = 0.f;
#pragma unroll 8
    for (int d = 0; d < 64; ++d) {
      float b0 = sb[wv][64 + d];
      float b1 = sb[wv][128 + d];
      o = fmaf(P0[d * 64 + lane], b0, o);
      o = fmaf(P1[d * 64 + lane], b1, o);
    }
    eo[side] = o;
  }
  float pd = eo[0] * eo[1];
#pragma unroll
  for (int o = 32; o; o >>= 1) pd += __shfl_xor(pd, o);
  if (lane == 0) out[w] = pd;
}

extern "C" void kernel_launch(void* const* d_in, const int* in_sizes, int n_in,
                              void* d_out, int out_size, void* d_ws, size_t ws_size,
                              hipStream_t stream) {
  const int* edge_src = (const int*)d_in[0];
  const int* edge_dst = (const int*)d_in[1];
  const float* edge_val = (const float*)d_in[2];
  const float* U_emb = (const float*)d_in[3];
  const float* V_emb = (const float*)d_in[4];
  const float* Wq = (const float*)d_in[5];
  const float* Wk = (const float*)d_in[6];
  const float* Wv = (const float*)d_in[7];
  const float* Wo = (const float*)d_in[8];
  const int* u = (const int*)d_in[9];
  const int* ii = (const int*)d_in[10];
  float* out = (float*)d_out;

  const float4* U4 = (const float4*)U_emb;
  const float4* V4 = (const float4*)V_emb;

  // workspace layout (16B-aligned base)
  float* Ea = (float*)d_ws;                          // H0 | H1 (fp16 tables, 25.6MB each)
  float* Eb = Ea + (size_t)NN * DD;                  // H2 (aliases c_sv scratch before)
  float* Es = Eb + (size_t)NN * DD;                  // n2list scratch region
  float* Mt = Es + (size_t)4 * NS * DD;              // 2*4096
  float* Pm = Mt + 8192;                             // 2*4096
  int* row_ptr = (int*)(Pm + 8192);                  // NN+1 (+pad)
  int* bcur = row_ptr + NN + 4;                      // NB2
  int* snodes = bcur + NB2;                          // NS
  int* n2cnt = snodes + NS;                          // 1
  uintptr_t pa = (uintptr_t)(n2cnt + 1);
  pa = (pa + 15) & ~(uintptr_t)15;
  int2* pairs = (int2*)pa;                           // NE int2

  uint2* H0 = (uint2*)Ea;                 // NN*16 uint2
  uint2* H1 = H0 + (size_t)NN * 16;
  uint2* H2 = (uint2*)Eb;                 // written after c_sv dead
  int2* c_sv = (int2*)Eb;                 // NB2*BCAP int2 = 12.8MB — dead after k_fine4m
  int* n2list = (int*)Es;                 // Es region (no other use)

  k_pre<<<1, 256, 0, stream>>>(bcur, n2cnt);
  k_coarse2<<<CB, 256, 0, stream>>>(edge_src, edge_dst, edge_val, bcur, c_sv);
  k_fine4m<<<FB + CONVB + PREPB + BSB, 256, 0, stream>>>(bcur, c_sv, pairs, row_ptr, U4, V4, H0,
                                                         Wq, Wk, Wv, Wo, Mt, Pm, u, ii, snodes);
  k_prop1m<<<P1B + NLB, 256, 0, stream>>>(H0, H1, snodes, row_ptr, pairs, n2list, n2cnt);
  k_stage2<<<1536, 256, 0, stream>>>(H1, H2, row_ptr, pairs, n2list, n2cnt);
  k_attn4<<<(BB + 3) / 4, 256, 0, stream>>>(U_emb, V_emb, (const __half*)H1, (const __half*)H2,
                                            snodes, row_ptr, pairs, Mt, Pm, out);
}